// Round 1
// baseline (400.503 us; speedup 1.0000x reference)
//
#include <hip/hip_runtime.h>

typedef __bf16 bf16_t;
typedef __bf16 bf16x8 __attribute__((ext_vector_type(8)));
typedef float f32x4 __attribute__((ext_vector_type(4)));

#define KN 50

// packed weight layout in d_ws (all bf16, [col][k] i.e. transposed):
// W1t: [64][96]  (k 72..95 zero-padded)
// W2t: [64][64]
// A1t: [64][128]
// A2t: [64][64]
#define W1T_ELEMS 6144
#define W2T_ELEMS 4096
#define A1T_ELEMS 8192
#define A2T_ELEMS 4096
#define TOTW (W1T_ELEMS + W2T_ELEMS + A1T_ELEMS + A2T_ELEMS)
#define W2T_OFF (W1T_ELEMS)
#define A1T_OFF (W1T_ELEMS + W2T_ELEMS)
#define A2T_OFF (W1T_ELEMS + W2T_ELEMS + A1T_ELEMS)

__global__ __launch_bounds__(256) void pack_weights_k(
    const float* __restrict__ w1, const float* __restrict__ w2,
    const float* __restrict__ a1, const float* __restrict__ a2,
    bf16_t* __restrict__ wp)
{
  int idx = blockIdx.x * 256 + threadIdx.x;
  if (idx >= TOTW) return;
  float v;
  if (idx < W1T_ELEMS) {
    int n = idx / 96, k = idx % 96;           // W1t[n][k] = w1[k][n], pad k>=72
    v = (k < 72) ? w1[k * 64 + n] : 0.f;
  } else if (idx < A1T_OFF) {
    int e = idx - W2T_OFF; int n = e >> 6, k = e & 63;
    v = w2[k * 64 + n];
  } else if (idx < A2T_OFF) {
    int e = idx - A1T_OFF; int n = e >> 7, k = e & 127;
    v = a1[k * 64 + n];
  } else {
    int e = idx - A2T_OFF; int n = e >> 6, k = e & 63;
    v = a2[k * 64 + n];
  }
  wp[idx] = (bf16_t)v;
}

__global__ __launch_bounds__(256) void social_agg_k(
    const int* __restrict__ nodes,
    const int* __restrict__ nidx,
    const int* __restrict__ nlen,
    const float* __restrict__ labels,
    const float* __restrict__ u2e,
    const float* __restrict__ b1v,
    const float* __restrict__ b2v,
    const float* __restrict__ ab1v,
    const float* __restrict__ ab2v,
    const float* __restrict__ a3w,
    const float* __restrict__ a3b,
    const bf16_t* __restrict__ wp,
    float* __restrict__ out)
{
  // LDS: row pads chosen to keep <=2-way bank aliasing for b128 frag reads
  __shared__ __align__(16) bf16_t Xs[64][104];  // X = [e_u | labels | 0], Kpad=96
  __shared__ __align__(16) bf16_t Hs[64][72];   // stage1 out / stage3 out (reused)
  __shared__ __align__(16) bf16_t Os[64][72];   // o_history (bf16, mfma operand)
  __shared__ float Osf[64][68];                 // o_history fp32 (for aggregate)
  __shared__ __align__(16) bf16_t urb[64];      // u_rep bf16
  __shared__ float urf[64];                     // u_rep fp32 (fallback)
  __shared__ float sco[64];
  __shared__ float att[64];
  __shared__ float part[4][64];

  const int b    = blockIdx.x;
  const int tid  = threadIdx.x;
  const int lane = tid & 63;
  const int w    = tid >> 6;
  const int m0   = w * 16;
  const int lrow = lane & 15;   // A-row / B-col / C-col
  const int lg   = lane >> 4;   // k-group / C row-group
  const int len  = nlen[b];
  const int node = nodes[b];

  // ---- build X in LDS: row r = neighbor k, cols [0,64)=e_u bf16, [64,72)=labels, [72,96)=0
  {
    const int r = tid >> 2;   // 0..63
    const int p = tid & 3;
    if (r < KN) {
      const int gi = nidx[b * KN + r];
      const float* src = u2e + (size_t)gi * 64;
#pragma unroll
      for (int j = 0; j < 4; ++j) {
        const int c = p * 4 + j * 16;   // 4 lanes cover a contiguous 64B chunk per j
        float4 v = *reinterpret_cast<const float4*>(src + c);
        Xs[r][c + 0] = (bf16_t)v.x;
        Xs[r][c + 1] = (bf16_t)v.y;
        Xs[r][c + 2] = (bf16_t)v.z;
        Xs[r][c + 3] = (bf16_t)v.w;
      }
      if (p == 0) {
        const float* lb = labels + ((size_t)b * KN + r) * 8;
#pragma unroll
        for (int j = 0; j < 8; ++j) Xs[r][64 + j] = (bf16_t)lb[j];
#pragma unroll
        for (int j = 0; j < 24; ++j) Xs[r][72 + j] = (bf16_t)0.f;
      }
    } else {
      // pad rows: zeros (finite garbage downstream, masked out of softmax)
#pragma unroll
      for (int j = 0; j < 4; ++j) {
        const int c = p * 4 + j * 16;
        Xs[r][c + 0] = (bf16_t)0.f; Xs[r][c + 1] = (bf16_t)0.f;
        Xs[r][c + 2] = (bf16_t)0.f; Xs[r][c + 3] = (bf16_t)0.f;
      }
      if (p == 0) {
#pragma unroll
        for (int j = 0; j < 32; ++j) Xs[r][64 + j] = (bf16_t)0.f;
      }
    }
  }
  if (tid < 64) {
    float v = u2e[(size_t)node * 64 + tid];
    urf[tid] = v;
    urb[tid] = (bf16_t)v;
  }
  __syncthreads();

  const bf16_t* W1t = wp;
  const bf16_t* W2t = wp + W2T_OFF;
  const bf16_t* A1t = wp + A1T_OFF;
  const bf16_t* A2t = wp + A2T_OFF;

  const f32x4 zero4 = {0.f, 0.f, 0.f, 0.f};
  f32x4 acc[4];

  // ================= stage 1: H = relu(X @ W1 + b1), K=96 =================
#pragma unroll
  for (int t = 0; t < 4; ++t) acc[t] = zero4;
#pragma unroll
  for (int s = 0; s < 3; ++s) {
    bf16x8 af = *reinterpret_cast<const bf16x8*>(&Xs[m0 + lrow][s * 32 + lg * 8]);
#pragma unroll
    for (int t = 0; t < 4; ++t) {
      bf16x8 bf_ = *reinterpret_cast<const bf16x8*>(W1t + (t * 16 + lrow) * 96 + s * 32 + lg * 8);
      acc[t] = __builtin_amdgcn_mfma_f32_16x16x32_bf16(af, bf_, acc[t], 0, 0, 0);
    }
  }
#pragma unroll
  for (int t = 0; t < 4; ++t) {
    const int col = t * 16 + lrow;
    const float bias = b1v[col];
#pragma unroll
    for (int r = 0; r < 4; ++r) {
      float v = acc[t][r] + bias;
      v = v > 0.f ? v : 0.f;
      Hs[m0 + lg * 4 + r][col] = (bf16_t)v;
    }
  }

  // ================= stage 2: O = relu(H @ W2 + b2), K=64 =================
#pragma unroll
  for (int t = 0; t < 4; ++t) acc[t] = zero4;
#pragma unroll
  for (int s = 0; s < 2; ++s) {
    bf16x8 af = *reinterpret_cast<const bf16x8*>(&Hs[m0 + lrow][s * 32 + lg * 8]);
#pragma unroll
    for (int t = 0; t < 4; ++t) {
      bf16x8 bf_ = *reinterpret_cast<const bf16x8*>(W2t + (t * 16 + lrow) * 64 + s * 32 + lg * 8);
      acc[t] = __builtin_amdgcn_mfma_f32_16x16x32_bf16(af, bf_, acc[t], 0, 0, 0);
    }
  }
#pragma unroll
  for (int t = 0; t < 4; ++t) {
    const int col = t * 16 + lrow;
    const float bias = b2v[col];
#pragma unroll
    for (int r = 0; r < 4; ++r) {
      float v = acc[t][r] + bias;
      v = v > 0.f ? v : 0.f;
      const int row = m0 + lg * 4 + r;
      Os[row][col]  = (bf16_t)v;
      Osf[row][col] = v;          // fp32 copy for the final aggregate
    }
  }

  // ============ stage 3: A1 = relu([O | u_rep] @ a1W + a1b), K=128 ============
#pragma unroll
  for (int t = 0; t < 4; ++t) acc[t] = zero4;
#pragma unroll
  for (int s = 0; s < 4; ++s) {
    bf16x8 af;
    if (s < 2) af = *reinterpret_cast<const bf16x8*>(&Os[m0 + lrow][s * 32 + lg * 8]);
    else       af = *reinterpret_cast<const bf16x8*>(&urb[(s - 2) * 32 + lg * 8]); // row-broadcast
#pragma unroll
    for (int t = 0; t < 4; ++t) {
      bf16x8 bf_ = *reinterpret_cast<const bf16x8*>(A1t + (t * 16 + lrow) * 128 + s * 32 + lg * 8);
      acc[t] = __builtin_amdgcn_mfma_f32_16x16x32_bf16(af, bf_, acc[t], 0, 0, 0);
    }
  }
#pragma unroll
  for (int t = 0; t < 4; ++t) {
    const int col = t * 16 + lrow;
    const float bias = ab1v[col];
#pragma unroll
    for (int r = 0; r < 4; ++r) {
      float v = acc[t][r] + bias;
      v = v > 0.f ? v : 0.f;
      Hs[m0 + lg * 4 + r][col] = (bf16_t)v;   // reuse Hs
    }
  }

  // ======= stage 4: A2 = relu(A1 @ a2W + a2b), K=64; scores = A2 @ a3 + b3 =======
#pragma unroll
  for (int t = 0; t < 4; ++t) acc[t] = zero4;
#pragma unroll
  for (int s = 0; s < 2; ++s) {
    bf16x8 af = *reinterpret_cast<const bf16x8*>(&Hs[m0 + lrow][s * 32 + lg * 8]);
#pragma unroll
    for (int t = 0; t < 4; ++t) {
      bf16x8 bf_ = *reinterpret_cast<const bf16x8*>(A2t + (t * 16 + lrow) * 64 + s * 32 + lg * 8);
      acc[t] = __builtin_amdgcn_mfma_f32_16x16x32_bf16(af, bf_, acc[t], 0, 0, 0);
    }
  }
  {
    float pr[4] = {0.f, 0.f, 0.f, 0.f};
#pragma unroll
    for (int t = 0; t < 4; ++t) {
      const int col = t * 16 + lrow;
      const float bias = ab2v[col];
      const float a3c  = a3w[col];
#pragma unroll
      for (int r = 0; r < 4; ++r) {
        float v = acc[t][r] + bias;
        v = v > 0.f ? v : 0.f;
        pr[r] += v * a3c;
      }
    }
    // reduce across the 16 lanes sharing lg (cols) -> score per row
#pragma unroll
    for (int r = 0; r < 4; ++r) {
#pragma unroll
      for (int m = 1; m < 16; m <<= 1) pr[r] += __shfl_xor(pr[r], m, 64);
    }
    if (lrow == 0) {
      const float a3bias = a3b[0];
#pragma unroll
      for (int r = 0; r < 4; ++r) sco[m0 + lg * 4 + r] = pr[r] + a3bias;
    }
  }
  __syncthreads();

  // ================= masked softmax over 64 rows (wave 0) =================
  if (w == 0) {
    const bool valid = lane < len;
    float s = valid ? sco[lane] : -1e30f;
    float m = s;
#pragma unroll
    for (int k = 1; k < 64; k <<= 1) m = fmaxf(m, __shfl_xor(m, k, 64));
    float e = valid ? __expf(s - m) : 0.f;
    float sm = e;
#pragma unroll
    for (int k = 1; k < 64; k <<= 1) sm += __shfl_xor(sm, k, 64);
    att[lane] = (sm > 0.f) ? e / sm : 0.f;
  }
  __syncthreads();

  // ================= aggregate: agg[d] = sum_k att[k] * O[k][d] =================
  {
    const int d = tid & 63;
    const int g = tid >> 6;
    float a = 0.f;
#pragma unroll
    for (int k2 = 0; k2 < 16; ++k2) {
      const int kk = g * 16 + k2;
      a += att[kk] * Osf[kk][d];
    }
    part[g][d] = a;
  }
  __syncthreads();
  if (tid < 64) {
    float v = part[0][tid] + part[1][tid] + part[2][tid] + part[3][tid];
    out[(size_t)b * 64 + tid] = (len > 0) ? v : urf[tid];
  }
}

extern "C" void kernel_launch(void* const* d_in, const int* in_sizes, int n_in,
                              void* d_out, int out_size, void* d_ws, size_t ws_size,
                              hipStream_t stream) {
  (void)in_sizes; (void)n_in; (void)out_size; (void)ws_size;
  const int*   nodes  = (const int*)d_in[0];
  const int*   nidx   = (const int*)d_in[1];
  const int*   nlen   = (const int*)d_in[2];
  const float* labels = (const float*)d_in[3];
  const float* u2e    = (const float*)d_in[4];
  const float* w1W    = (const float*)d_in[5];
  const float* w1b    = (const float*)d_in[6];
  const float* w2W    = (const float*)d_in[7];
  const float* w2b    = (const float*)d_in[8];
  const float* a1W    = (const float*)d_in[9];
  const float* a1b    = (const float*)d_in[10];
  const float* a2W    = (const float*)d_in[11];
  const float* a2b    = (const float*)d_in[12];
  const float* a3W    = (const float*)d_in[13];
  const float* a3b    = (const float*)d_in[14];
  float* out = (float*)d_out;
  bf16_t* wp = (bf16_t*)d_ws;

  pack_weights_k<<<(TOTW + 255) / 256, 256, 0, stream>>>(w1W, w2W, a1W, a2W, wp);
  social_agg_k<<<16384, 256, 0, stream>>>(nodes, nidx, nlen, labels, u2e,
                                          w1b, w2b, a1b, a2b, a3W, a3b, wp, out);
}